// Round 13
// baseline (103.732 us; speedup 1.0000x reference)
//
#include <hip/hip_runtime.h>

// SS2D: B=32,H=32,W=32,DM=128, DIN=64, N=16, R=8, L=1024
// Layouts: xc,u,delta,y = (b,d,l); z = (b,l,d); Bs,Cs = (b,n,l); out = (b,l,dm)

typedef __attribute__((ext_vector_type(8))) short short8;
typedef __attribute__((ext_vector_type(4))) float floatx4;

// split fp32 -> bf16 hi + bf16 lo (truncation; 2-term ~2^-17 rel accuracy)
__device__ __forceinline__ void cvt_split8(const float* v, short8& hi, short8& lo) {
#pragma unroll
    for (int i = 0; i < 8; ++i) {
        const unsigned xb = __float_as_uint(v[i]);
        hi[i] = (short)(xb >> 16);
        const float lf = v[i] - __uint_as_float(xb & 0xFFFF0000u);
        lo[i] = (short)(__float_as_uint(lf) >> 16);
    }
}

// ---------------- K1: xz = x @ w_in^T via dual-bf16 MFMA ---------------------
// 512 blocks x 256 threads (4 waves). Wave w: rows m0=w*16 (16 pixels) x all
// 128 outputs (8 N-tiles). A/B fragments loaded directly from global
// (8 consecutive k per lane), split to bf16 hi/lo, 3 MFMAs per tile/k-step.
// Epilogue: acc -> LDS bounce -> coalesced xc (b,d,l) and z (b,l,d) stores.
__global__ __launch_bounds__(256) void k1_gemm_in(
    const float* __restrict__ x, const float* __restrict__ w_in,
    float* __restrict__ xc, float* __restrict__ z)
{
    __shared__ float Cls[64 * 132];
    const int t    = threadIdx.x;
    const int p0   = blockIdx.x * 64;
    const int w    = t >> 6;
    const int l    = t & 63;
    const int lrow = l & 15, lk = l >> 4;
    const int m0   = w * 16;

    floatx4 acc[8];
#pragma unroll
    for (int nt = 0; nt < 8; ++nt) acc[nt] = (floatx4){0.f, 0.f, 0.f, 0.f};

#pragma unroll
    for (int ks = 0; ks < 4; ++ks) {
        const int k0 = ks * 32 + lk * 8;
        float av[8];
        {
            const float* ap = x + (size_t)(p0 + m0 + lrow) * 128 + k0;
            *reinterpret_cast<float4*>(&av[0]) = *reinterpret_cast<const float4*>(ap);
            *reinterpret_cast<float4*>(&av[4]) = *reinterpret_cast<const float4*>(ap + 4);
        }
        short8 ahi, alo;
        cvt_split8(av, ahi, alo);
#pragma unroll
        for (int nt = 0; nt < 8; ++nt) {
            float bv[8];
            const float* bp = w_in + (size_t)(nt * 16 + lrow) * 128 + k0;
            *reinterpret_cast<float4*>(&bv[0]) = *reinterpret_cast<const float4*>(bp);
            *reinterpret_cast<float4*>(&bv[4]) = *reinterpret_cast<const float4*>(bp + 4);
            short8 bhi, blo;
            cvt_split8(bv, bhi, blo);
            acc[nt] = __builtin_amdgcn_mfma_f32_16x16x32_bf16(ahi, bhi, acc[nt], 0, 0, 0);
            acc[nt] = __builtin_amdgcn_mfma_f32_16x16x32_bf16(ahi, blo, acc[nt], 0, 0, 0);
            acc[nt] = __builtin_amdgcn_mfma_f32_16x16x32_bf16(alo, bhi, acc[nt], 0, 0, 0);
        }
    }

    // acc -> LDS: row = m0 + lk*4 + r, col = nt*16 + lrow
#pragma unroll
    for (int nt = 0; nt < 8; ++nt)
#pragma unroll
        for (int r = 0; r < 4; ++r)
            Cls[(m0 + lk * 4 + r) * 132 + nt * 16 + lrow] = acc[nt][r];
    __syncthreads();

    const int b = p0 >> 10, lbase = p0 & 1023;
    {   // xc (b,e,l): thread = (e = t>>2, 16-pixel group)
        const int e  = t >> 2;
        const int pg = (t & 3) * 16;
        float tmp[16];
#pragma unroll
        for (int j = 0; j < 16; ++j) tmp[j] = Cls[(pg + j) * 132 + e];
        float* dst = xc + ((size_t)b * 64 + e) * 1024 + lbase + pg;
#pragma unroll
        for (int q = 0; q < 4; ++q)
            *reinterpret_cast<float4*>(dst + q * 4) =
                make_float4(tmp[q*4], tmp[q*4+1], tmp[q*4+2], tmp[q*4+3]);
    }
    {   // z (b,l,d): thread = (pix = t>>2, 16-d group)
        const int pix = t >> 2;
        const int dq  = (t & 3) * 16;
        const float* srcr = &Cls[pix * 132 + 64 + dq];
        float* dst = z + ((size_t)p0 + pix) * 64 + dq;
#pragma unroll
        for (int q = 0; q < 4; ++q)
            *reinterpret_cast<float4*>(dst + q * 4) =
                *reinterpret_cast<const float4*>(srcr + q * 4);
    }
}

// ---------------- K2: depthwise 3x3 conv + bias + SiLU -> u (b,d,l) ----------
__global__ __launch_bounds__(256) void k2_conv(
    const float* __restrict__ xc, const float* __restrict__ cw,
    const float* __restrict__ cb, float* __restrict__ u)
{
    __shared__ float pl[1024];
    const int bd = blockIdx.x;
    const int t  = threadIdx.x;
    const int d  = bd & 63;
    reinterpret_cast<float4*>(pl)[t] =
        reinterpret_cast<const float4*>(xc + (size_t)bd * 1024)[t];
    float w[9];
#pragma unroll
    for (int i = 0; i < 9; ++i) w[i] = cw[d * 9 + i];
    const float bias = cb[d];
    __syncthreads();
    float o[4];
#pragma unroll
    for (int i = 0; i < 4; ++i) {
        const int p  = t * 4 + i;
        const int py = p >> 5, px = p & 31;
        float s = 0.f;
#pragma unroll
        for (int ky = 0; ky < 3; ++ky) {
            const int iy = py + ky - 1;
            if (iy < 0 || iy > 31) continue;
#pragma unroll
            for (int kx = 0; kx < 3; ++kx) {
                const int ix = px + kx - 1;
                if (ix < 0 || ix > 31) continue;
                s = fmaf(pl[iy * 32 + ix], w[ky * 3 + kx], s);
            }
        }
        s += bias;
        o[i] = s / (1.f + __expf(-s));
    }
    reinterpret_cast<float4*>(u + (size_t)bd * 1024)[t] = make_float4(o[0], o[1], o[2], o[3]);
}

// ---------------- K3: x-proj (40 ch) + dt-proj + softplus --------------------
__global__ __launch_bounds__(64) void k3_xproj(
    const float* __restrict__ u, const float* __restrict__ xpw,
    const float* __restrict__ dtw_g, const float* __restrict__ dtb,
    float* __restrict__ delta, float* __restrict__ Bsp, float* __restrict__ Csp)
{
    __shared__ float ut[64][36];   // [d][pix], pad 4
    __shared__ float xw[64 * 40];  // [d][ch]
    __shared__ float xd8[8][36];   // [ch<8][pix]
    __shared__ float dwv[64 * 9];  // [d][r] stride 9
    const int t   = threadIdx.x;
    const int blk = blockIdx.x;
    const int b   = blk >> 5;
    const int l0  = (blk & 31) * 32;

#pragma unroll 4
    for (int c = 0; c < 40; ++c)
        xw[t * 40 + c] = xpw[(size_t)c * 64 + t];
#pragma unroll
    for (int k = 0; k < 8; ++k)
        dwv[t * 9 + k] = dtw_g[t * 8 + k];
    {
        const float* ub = u + (size_t)b * 65536 + l0;
#pragma unroll
        for (int i = t; i < 512; i += 64) {
            const int dd = i >> 3, pq = i & 7;
            const float4 v = *reinterpret_cast<const float4*>(ub + (size_t)dd * 1024 + pq * 4);
            *reinterpret_cast<float4*>(&ut[dd][pq * 4]) = v;
        }
    }
    __syncthreads();

    const int pixq = t & 7;
    const int cg   = t >> 3;
    const int c0   = cg * 5;
    float4 acc[5];
#pragma unroll
    for (int j = 0; j < 5; ++j) acc[j] = make_float4(0.f, 0.f, 0.f, 0.f);
#pragma unroll 8
    for (int dd = 0; dd < 64; ++dd) {
        const float4 uv = *reinterpret_cast<const float4*>(&ut[dd][pixq * 4]);
        const float* row = &xw[dd * 40 + c0];
#pragma unroll
        for (int j = 0; j < 5; ++j) {
            const float w = row[j];
            acc[j].x = fmaf(w, uv.x, acc[j].x);
            acc[j].y = fmaf(w, uv.y, acc[j].y);
            acc[j].z = fmaf(w, uv.z, acc[j].z);
            acc[j].w = fmaf(w, uv.w, acc[j].w);
        }
    }
#pragma unroll
    for (int j = 0; j < 5; ++j) {
        const int c = c0 + j;
        if (c < 8) {
            *reinterpret_cast<float4*>(&xd8[c][pixq * 4]) = acc[j];
        } else if (c < 24) {
            *reinterpret_cast<float4*>(Bsp + (size_t)b * 16384 +
                (size_t)(c - 8) * 1024 + l0 + pixq * 4) = acc[j];
        } else {
            *reinterpret_cast<float4*>(Csp + (size_t)b * 16384 +
                (size_t)(c - 24) * 1024 + l0 + pixq * 4) = acc[j];
        }
    }
    __syncthreads();

    const int dg = t >> 3;
    float dts[4][8];
#pragma unroll
    for (int e = 0; e < 4; ++e)
#pragma unroll
        for (int r = 0; r < 8; ++r)
            dts[e][r] = xd8[r][pixq * 4 + e];
    float* dp = delta + (size_t)b * 65536 + l0 + pixq * 4;
#pragma unroll
    for (int k = 0; k < 8; ++k) {
        const int dd = dg * 8 + k;
        const float* r8 = &dwv[dd * 9];
        const float bias = dtb[dd];
        float ov[4];
#pragma unroll
        for (int e = 0; e < 4; ++e) {
            float s = bias;
#pragma unroll
            for (int r = 0; r < 8; ++r) s = fmaf(dts[e][r], r8[r], s);
            ov[e] = fmaxf(s, 0.f) + log1pf(__expf(-fabsf(s)));
        }
        *reinterpret_cast<float4*>(dp + (size_t)dd * 1024) =
            make_float4(ov[0], ov[1], ov[2], ov[3]);
    }
}

// ---------------- K4: timestep-major chunked scan (block per (b,d)) ----------
__global__ __launch_bounds__(256) void k4_scan(
    const float* __restrict__ delta, const float* __restrict__ u,
    const float* __restrict__ Bsp, const float* __restrict__ Csp,
    const float* __restrict__ A_logs, const float* __restrict__ Ds,
    float* __restrict__ y)
{
    __shared__ float Ps[256][17];
    __shared__ float qs[256][17];
    __shared__ float Sp[16][17];
    __shared__ float Sq[16][17];
    const int t = threadIdx.x;
    const int pair = blockIdx.x;    // b*64 + d
    const int b = pair >> 6, d = pair & 63;

    float A[16];
#pragma unroll
    for (int n = 0; n < 16; ++n) A[n] = -__expf(A_logs[d * 16 + n]);

    const float4 d4 = *reinterpret_cast<const float4*>(delta + (size_t)pair * 1024 + t * 4);
    const float4 u4 = *reinterpret_cast<const float4*>(u     + (size_t)pair * 1024 + t * 4);
    const float du0 = d4.x * u4.x, du1 = d4.y * u4.y;
    const float du2 = d4.z * u4.z, du3 = d4.w * u4.w;

    const float* Bb = Bsp + (size_t)b * 16384 + t * 4;
    const float* Cb = Csp + (size_t)b * 16384 + t * 4;

#pragma unroll
    for (int n = 0; n < 16; ++n) {
        const float4 B4 = *reinterpret_cast<const float4*>(Bb + n * 1024);
        float a, P, q;
        a = __expf(d4.x * A[n]); P = a;   q = du0 * B4.x;
        a = __expf(d4.y * A[n]); P *= a;  q = fmaf(a, q, du1 * B4.y);
        a = __expf(d4.z * A[n]); P *= a;  q = fmaf(a, q, du2 * B4.z);
        a = __expf(d4.w * A[n]); P *= a;  q = fmaf(a, q, du3 * B4.w);
        Ps[t][n] = P; qs[t][n] = q;
    }
    __syncthreads();

    const int n = t >> 4, g = t & 15;
    float rp[16], rq[16];
    {
        float Pseg = 1.f, qseg = 0.f;
#pragma unroll
        for (int i = 0; i < 16; ++i) {
            const int c = g * 16 + i;
            rp[i] = Ps[c][n]; rq[i] = qs[c][n];
            qseg = fmaf(rp[i], qseg, rq[i]);
            Pseg *= rp[i];
        }
        Sp[g][n] = Pseg; Sq[g][n] = qseg;
    }
    __syncthreads();
    if (t < 16) {
        float h = 0.f;
#pragma unroll
        for (int s = 0; s < 16; ++s) {
            const float Pv = Sp[s][t], qv = Sq[s][t];
            Sp[s][t] = h;
            h = fmaf(Pv, h, qv);
        }
    }
    __syncthreads();
    {
        float h = Sp[g][n];
#pragma unroll
        for (int i = 0; i < 16; ++i) {
            const int c = g * 16 + i;
            qs[c][n] = h;
            h = fmaf(rp[i], h, rq[i]);
        }
    }
    __syncthreads();

    const float Dval = Ds[d];
    float y0 = Dval * u4.x, y1 = Dval * u4.y, y2 = Dval * u4.z, y3 = Dval * u4.w;
#pragma unroll
    for (int nn = 0; nn < 16; ++nn) {
        const float4 B4 = *reinterpret_cast<const float4*>(Bb + nn * 1024);
        const float4 C4 = *reinterpret_cast<const float4*>(Cb + nn * 1024);
        float h = qs[t][nn];
        float a;
        a = __expf(d4.x * A[nn]); h = fmaf(a, h, du0 * B4.x); y0 = fmaf(h, C4.x, y0);
        a = __expf(d4.y * A[nn]); h = fmaf(a, h, du1 * B4.y); y1 = fmaf(h, C4.y, y1);
        a = __expf(d4.z * A[nn]); h = fmaf(a, h, du2 * B4.z); y2 = fmaf(h, C4.z, y2);
        a = __expf(d4.w * A[nn]); h = fmaf(a, h, du3 * B4.w); y3 = fmaf(h, C4.w, y3);
    }
    *reinterpret_cast<float4*>(y + (size_t)pair * 1024 + t * 4) =
        make_float4(y0, y1, y2, y3);
}

// ---------------- K5: LayerNorm + silu(z) gate + out GEMM --------------------
__global__ __launch_bounds__(256) void k5_out(
    const float* __restrict__ y, const float* __restrict__ z,
    const float* __restrict__ ln_g, const float* __restrict__ ln_b,
    const float* __restrict__ w_out, float* __restrict__ out)
{
    __shared__ float yn[64 * 68];   // [l_local][d] stride 68
    __shared__ float wo[64 * 132];  // [d][c] pad 132
    const int t  = threadIdx.x;
    const int p0 = blockIdx.x * 64;
    const int b  = p0 >> 10, l0 = p0 & 1023;

    for (int i = t; i < 8192; i += 256) {
        const int c = i >> 6, dd = i & 63;
        wo[dd * 132 + c] = w_out[i];
    }

    {
        const int d = t >> 2;
        const float* yrow = y + ((size_t)b * 64 + d) * 1024 + l0;
#pragma unroll
        for (int k = 0; k < 4; ++k) {
            const int c4 = ((t & 3) + k * 4) * 4;
            const float4 v = *reinterpret_cast<const float4*>(&yrow[c4]);
            yn[(c4 + 0) * 68 + d] = v.x;
            yn[(c4 + 1) * 68 + d] = v.y;
            yn[(c4 + 2) * 68 + d] = v.z;
            yn[(c4 + 3) * 68 + d] = v.w;
        }
    }
    __syncthreads();

    const int lane = t & 63, wv = t >> 6;
    const float g = ln_g[lane], bbv = ln_b[lane];
#pragma unroll 1
    for (int i = 0; i < 16; ++i) {
        const int pl = wv * 16 + i;
        const size_t p = (size_t)p0 + pl;
        const float v  = yn[pl * 68 + lane];
        const float zv = z[p * 64 + lane];
        float s1 = v, s2 = v * v;
#pragma unroll
        for (int m = 1; m < 64; m <<= 1) {
            s1 += __shfl_xor(s1, m);
            s2 += __shfl_xor(s2, m);
        }
        const float mu   = s1 * (1.f / 64.f);
        const float var  = s2 * (1.f / 64.f) - mu * mu;
        const float rstd = rsqrtf(var + 1e-5f);
        const float sz   = zv / (1.f + __expf(-zv));
        yn[pl * 68 + lane] = ((v - mu) * rstd * g + bbv) * sz;
    }
    __syncthreads();

    const int tx = t & 31, ty = t >> 5;
    float acc[8][4];
#pragma unroll
    for (int i = 0; i < 8; ++i)
#pragma unroll
        for (int j = 0; j < 4; ++j) acc[i][j] = 0.f;

    for (int dd = 0; dd < 64; ++dd) {
        const float4 w4 = *reinterpret_cast<const float4*>(&wo[dd * 132 + (tx << 2)]);
#pragma unroll
        for (int i = 0; i < 8; ++i) {
            const float a = yn[(ty * 8 + i) * 68 + dd];
            acc[i][0] = fmaf(a, w4.x, acc[i][0]);
            acc[i][1] = fmaf(a, w4.y, acc[i][1]);
            acc[i][2] = fmaf(a, w4.z, acc[i][2]);
            acc[i][3] = fmaf(a, w4.w, acc[i][3]);
        }
    }
#pragma unroll
    for (int i = 0; i < 8; ++i) {
        const size_t p = (size_t)p0 + ty * 8 + i;
        *reinterpret_cast<float4*>(&out[p * 128 + (tx << 2)]) =
            make_float4(acc[i][0], acc[i][1], acc[i][2], acc[i][3]);
    }
}

extern "C" void kernel_launch(void* const* d_in, const int* in_sizes, int n_in,
                              void* d_out, int out_size, void* d_ws, size_t ws_size,
                              hipStream_t stream)
{
    const float* x        = (const float*)d_in[0];
    const float* w_in     = (const float*)d_in[1];
    const float* conv_w   = (const float*)d_in[2];
    const float* conv_b   = (const float*)d_in[3];
    const float* xproj_w  = (const float*)d_in[4];
    const float* dtproj_w = (const float*)d_in[5];
    const float* dtproj_b = (const float*)d_in[6];
    const float* A_logs   = (const float*)d_in[7];
    const float* Ds       = (const float*)d_in[8];
    const float* ln_g     = (const float*)d_in[9];
    const float* ln_b     = (const float*)d_in[10];
    const float* w_out    = (const float*)d_in[11];
    float* out = (float*)d_out;
    float* ws  = (float*)d_ws;

    const size_t M  = (size_t)2097152;  // 32*64*1024
    float* xc    = ws;                  // 8 MB
    float* z     = ws + M;              // 8 MB
    float* u     = ws + 2 * M;          // 8 MB
    float* delta = ws + 3 * M;          // 8 MB
    float* y     = ws + 4 * M;          // 8 MB  (b,d,l)
    float* Bsp   = ws + 5 * M;          // 2 MB
    float* Csp   = Bsp + 524288;        // 2 MB

    k1_gemm_in<<<512, 256, 0, stream>>>(x, w_in, xc, z);
    k2_conv<<<2048, 256, 0, stream>>>(xc, conv_w, conv_b, u);
    k3_xproj<<<1024, 64, 0, stream>>>(u, xproj_w, dtproj_w, dtproj_b, delta, Bsp, Csp);
    k4_scan<<<2048, 256, 0, stream>>>(delta, u, Bsp, Csp, A_logs, Ds, y);
    k5_out<<<512, 256, 0, stream>>>(y, z, ln_g, ln_b, w_out, out);
}